// Round 9
// baseline (48.377 us; speedup 1.0000x reference)
//
#include <hip/hip_runtime.h>

// Match XLA's elementwise f32 exactly: no FMA contraction on the decision path.
#pragma clang fp contract(off)

#define N_BOX   10647
#define N_CLS   80
#define ROW     85
#define CONF_T  0.8f
#define NMS_T   0.4f
#define NEGV    -1000000000.0f
#define KMAX    256       // max boxes per class (expected ~27)
#define OUT_N   3000
#define SURV_N  4096      // survivors cap (expected ~2000)
#define NBLK    80        // == N_CLS: one block per class in every phase
#define NTHR    256
#define ROWS_PB 136       // 80*136 >= 10647; 136*85*4 = 46240 B LDS, 16B-aligned
#define CTR_STRIDE 32     // one counter per 128B cacheline (kills MALL atomic serialization)
#define CTR_SURV (80 * CTR_STRIDE)
#define CTR_BAR  (81 * CTR_STRIDE)
#define CTR_BYTES (82 * 128)

typedef unsigned long long u64;
typedef unsigned int u32;

// MALL-coherent (cross-XCD safe, L2-bypassing) accessors.
#define AT_LD64(p)   __hip_atomic_load((p),  __ATOMIC_RELAXED, __HIP_MEMORY_SCOPE_AGENT)
#define AT_ST64(p,v) __hip_atomic_store((p), (v), __ATOMIC_RELAXED, __HIP_MEMORY_SCOPE_AGENT)
#define AT_LD32(p)   __hip_atomic_load((p),  __ATOMIC_RELAXED, __HIP_MEMORY_SCOPE_AGENT)
#define AT_ST32(p,v) __hip_atomic_store((p), (v), __ATOMIC_RELAXED, __HIP_MEMORY_SCOPE_AGENT)
#define AT_LDF(p)    __hip_atomic_load((p),  __ATOMIC_RELAXED, __HIP_MEMORY_SCOPE_AGENT)
#define AT_STF(p,v)  __hip_atomic_store((p), (v), __ATOMIC_RELAXED, __HIP_MEMORY_SCOPE_AGENT)

__device__ __forceinline__ u64 pack_ff(float a, float b) {
    union { float f[2]; u64 u; } x; x.f[0] = a; x.f[1] = b; return x.u;
}
__device__ __forceinline__ u64 pack_fi(float a, int b) {
    union { struct { float f; int i; } s; u64 u; } x; x.s.f = a; x.s.i = b; return x.u;
}
__device__ __forceinline__ float lo_f(u64 v) { union { u64 u; float f[2]; } x; x.u = v; return x.f[0]; }
__device__ __forceinline__ float hi_f(u64 v) { union { u64 u; float f[2]; } x; x.u = v; return x.f[1]; }
__device__ __forceinline__ int   hi_i(u64 v) { union { u64 u; int i[2]; } x; x.u = v; return x.i[1]; }

// Fence-free grid barrier: sc1 data is already at MALL when __syncthreads
// drains vmcnt, so arrival is one relaxed agent fetch_add; exit is a relaxed
// poll. Bounded spin: fails loud, never hangs.
__device__ __forceinline__ void grid_bar(int* bar, int target) {
    __syncthreads();
    if (threadIdx.x == 0) {
        __builtin_amdgcn_s_waitcnt(0);
        __hip_atomic_fetch_add(bar, 1, __ATOMIC_RELAXED, __HIP_MEMORY_SCOPE_AGENT);
        long guard = 0;
        while (__hip_atomic_load(bar, __ATOMIC_RELAXED, __HIP_MEMORY_SCOPE_AGENT) < target) {
            __builtin_amdgcn_s_sleep(2);
            if (++guard > (1L << 26)) break;
        }
    }
    __syncthreads();
}

__global__ __launch_bounds__(NTHR) void k_fused(const float* __restrict__ det,
                                                float* __restrict__ out,
                                                int* counters,
                                                u64* pA, u64* pB, u64* pS, u32* pC,
                                                float* surv) {
    __shared__ float lds[ROWS_PB * ROW];   // 46240 B, reused across phases
    __shared__ int nkeep, base;
    const int tid  = threadIdx.x;
    const int bid  = blockIdx.x;
    const int gidx = bid * NTHR + tid;
    int* bar = counters + CTR_BAR;

    // ---------------- Phase B: filter + argmax + bin (batch 0) ----------------
    {
        const int row0 = bid * ROWS_PB;
        int nrows = N_BOX - row0;
        if (nrows > ROWS_PB) nrows = ROWS_PB;
        if (nrows > 0) {
            const int nflt = nrows * ROW;
            const float* src = det + (size_t)row0 * ROW;  // 46240*bid bytes: 16B aligned
            const int n4 = nflt >> 2;
            float4* l4 = (float4*)lds;
            const float4* s4 = (const float4*)src;
            #pragma unroll 4
            for (int j = tid; j < n4; j += NTHR) l4[j] = s4[j];
            for (int j = (n4 << 2) + tid; j < nflt; j += NTHR) lds[j] = src[j];
            __syncthreads();
            if (tid < nrows) {
                const float* p = lds + tid * ROW;
                float obj = p[4];
                if (obj >= CONF_T) {
                    float cx = p[0], cy = p[1], w = p[2], h = p[3];
                    float hw = w / 2.0f, hh = h / 2.0f;
                    // first-argmax over 80 classes (strict > keeps first = jnp.argmax)
                    float best = p[5]; int bcls = 0;
                    for (int c = 1; c < N_CLS; ++c) {
                        float v = p[5 + c];
                        if (v > best) { best = v; bcls = c; }
                    }
                    int pos = atomicAdd(&counters[bcls * CTR_STRIDE], 1);  // own cacheline
                    if (pos < KMAX) {
                        int o = bcls * KMAX + pos;
                        AT_ST64(&pA[o], pack_ff(cx - hw, cy - hh));
                        AT_ST64(&pB[o], pack_ff(cx + hw, cy + hh));
                        AT_ST64(&pS[o], pack_fi(obj * best, row0 + tid));
                        AT_ST32(&pC[o], __float_as_uint(best));
                    }
                }
            }
        }
    }
    grid_bar(bar, NBLK);

    // ---------------- Phase C: per-class NMS (block == class) ----------------
    {
        // carve NMS arrays out of the staging LDS (9.25 KB < 46 KB)
        float* rsc   = lds;                        // [KMAX]
        int*   ridx  = (int*)(lds + KMAX);         // [KMAX]
        float* sx1   = lds + 2 * KMAX;
        float* sy1   = lds + 3 * KMAX;
        float* sx2   = lds + 4 * KMAX;
        float* sy2   = lds + 5 * KMAX;
        float* scf   = lds + 6 * KMAX;
        float* keepc = lds + 7 * KMAX;
        unsigned char* alive = (unsigned char*)(lds + 8 * KMAX);

        const int c = bid;
        if (tid == 0) nkeep = 0;
        int k = AT_LD32((u32*)&counters[c * CTR_STRIDE]);
        if (k > KMAX) k = KMAX;

        for (int i = tid; i < k; i += NTHR) {
            u64 si = AT_LD64(&pS[c * KMAX + i]);
            rsc[i] = lo_f(si); ridx[i] = hi_i(si);
        }
        __syncthreads();

        // rank = #{j : score[j] > score[i] or (==, idx[j] < idx[i])} -> stable desc
        for (int i = tid; i < k; i += NTHR) {
            float s = rsc[i]; int id = ridx[i]; int r = 0;
            for (int j = 0; j < k; ++j) {
                float sj = rsc[j];
                r += (sj > s) || (sj == s && ridx[j] < id);
            }
            int o = c * KMAX + i;
            u64 a = AT_LD64(&pA[o]);
            u64 b = AT_LD64(&pB[o]);
            sx1[r] = lo_f(a); sy1[r] = hi_f(a);
            sx2[r] = lo_f(b); sy2[r] = hi_f(b);
            scf[r] = __uint_as_float(AT_LD32(&pC[o]));
            alive[r] = 1;
        }
        __syncthreads();

        // greedy NMS with the reference's exact IoU arithmetic
        for (int i = 0; i < k; ++i) {
            bool a = (alive[i] != 0);
            __syncthreads();          // all read alive[i] before thread0 clears it
            if (a) {
                if (tid == 0) { keepc[nkeep++] = scf[i]; alive[i] = 0; }
                float px1 = sx1[i], py1 = sy1[i], px2 = sx2[i], py2 = sy2[i];
                float a1 = ((px2 - px1) + 1.0f) * ((py2 - py1) + 1.0f);
                for (int j = i + 1 + tid; j < k; j += NTHR) {
                    if (!alive[j]) continue;
                    float ix1 = fmaxf(px1, sx1[j]);
                    float iy1 = fmaxf(py1, sy1[j]);
                    float ix2 = fminf(px2, sx2[j]);
                    float iy2 = fminf(py2, sy2[j]);
                    float iw = fmaxf((ix2 - ix1) + 1.0f, 0.0f);
                    float ih = fmaxf((iy2 - iy1) + 1.0f, 0.0f);
                    float inter = iw * ih;
                    float a2 = ((sx2[j] - sx1[j]) + 1.0f) * ((sy2[j] - sy1[j]) + 1.0f);
                    float den = ((a1 + a2) - inter) + 1e-16f;
                    if (inter / den > NMS_T) alive[j] = 0;
                }
            }
            __syncthreads();          // suppression visible before next iteration
        }

        if (tid == 0) base = atomicAdd(&counters[CTR_SURV], nkeep);
        __syncthreads();
        int nb = nkeep, b = base;
        for (int i = tid; i < nb; i += NTHR) {
            int o = b + i;
            if (o < SURV_N) AT_STF(&surv[o], keepc[i]);
        }
    }
    grid_bar(bar, 2 * NBLK);

    // ---------------- Phase D: rank-scatter + tail fill ----------------
    // Ranks (ties broken by surv index) form a permutation of 0..m-1, so the
    // scatter covers out[0..m-1] exactly once; fill out[m..OUT_N-1] with NEG.
    {
        int m = AT_LD32((u32*)&counters[CTR_SURV]); if (m > SURV_N) m = SURV_N;
        float* slds = lds;                         // reuse staging LDS (16 KB max)
        for (int i = tid; i < m; i += NTHR) slds[i] = AT_LDF(&surv[i]);
        __syncthreads();

        const int lane = tid & 63;
        const int wid  = gidx >> 6;                      // 0..319
        for (int g = wid; g < m; g += NBLK * (NTHR / 64)) {
            const float v = slds[g];
            int cnt = 0;
            for (int j = lane; j < m; j += 64) {
                float sj = slds[j];
                cnt += (sj > v) || (sj == v && j < g);
            }
            #pragma unroll
            for (int off = 32; off > 0; off >>= 1) cnt += __shfl_down(cnt, off, 64);
            if (lane == 0 && cnt < OUT_N) out[cnt] = v;
        }
        for (int i = m + gidx; i < OUT_N; i += NBLK * NTHR) out[i] = NEGV;
    }
}

extern "C" void kernel_launch(void* const* d_in, const int* in_sizes, int n_in,
                              void* d_out, int out_size, void* d_ws, size_t ws_size,
                              hipStream_t stream) {
    const float* det = (const float*)d_in[0];
    float* out = (float*)d_out;

    const size_t NB = (size_t)N_CLS * KMAX;     // 20480 entries
    char* p = (char*)d_ws;
    int*   counters = (int*)p;  p += 16384;     // 82 spread counters (128B each)
    u64*   pA   = (u64*)p;      p += NB * 8;    // (x1,y1)
    u64*   pB   = (u64*)p;      p += NB * 8;    // (x2,y2)
    u64*   pS   = (u64*)p;      p += NB * 8;    // (score, idx)
    u32*   pC   = (u32*)p;      p += NB * 4;    // conf
    float* surv = (float*)p;                    // SURV_N floats

    hipMemsetAsync(d_ws, 0, CTR_BYTES, stream);   // counters + barrier, every call
    hipLaunchKernelGGL(k_fused, dim3(NBLK), dim3(NTHR), 0, stream,
                       det, out, counters, pA, pB, pS, pC, surv);
}

// Round 10
// 48.220 us; speedup vs baseline: 1.0032x; 1.0032x over previous
//
#include <hip/hip_runtime.h>

// Match XLA's elementwise f32 exactly: no FMA contraction on the decision path.
#pragma clang fp contract(off)

#define N_BOX   10647
#define N_CLS   80
#define ROW     85
#define CONF_T  0.8f
#define NMS_T   0.4f
#define NEGV    -1000000000.0f
#define KMAX    256       // max boxes per class (expected ~27)
#define OUT_N   3000
#define SURV_N  4096      // survivors cap (expected ~2000)
#define NBLK    80        // == N_CLS: one block per class in every phase
#define NTHR    256
#define ROWS_PB 136       // 80*136 >= 10647; 136*85*4 = 46240 B LDS, 16B-aligned
#define CTR_STRIDE 32     // one counter per 128B cacheline (kills MALL atomic serialization)
#define CTR_SURV (80 * CTR_STRIDE)
#define CTR_BAR  (81 * CTR_STRIDE)
#define CTR_BYTES (82 * 128)

typedef unsigned long long u64;
typedef unsigned int u32;

// MALL-coherent (cross-XCD safe, L2-bypassing) accessors.
#define AT_LD64(p)   __hip_atomic_load((p),  __ATOMIC_RELAXED, __HIP_MEMORY_SCOPE_AGENT)
#define AT_ST64(p,v) __hip_atomic_store((p), (v), __ATOMIC_RELAXED, __HIP_MEMORY_SCOPE_AGENT)
#define AT_LD32(p)   __hip_atomic_load((p),  __ATOMIC_RELAXED, __HIP_MEMORY_SCOPE_AGENT)
#define AT_ST32(p,v) __hip_atomic_store((p), (v), __ATOMIC_RELAXED, __HIP_MEMORY_SCOPE_AGENT)
#define AT_LDF(p)    __hip_atomic_load((p),  __ATOMIC_RELAXED, __HIP_MEMORY_SCOPE_AGENT)
#define AT_STF(p,v)  __hip_atomic_store((p), (v), __ATOMIC_RELAXED, __HIP_MEMORY_SCOPE_AGENT)

__device__ __forceinline__ u64 pack_ff(float a, float b) {
    union { float f[2]; u64 u; } x; x.f[0] = a; x.f[1] = b; return x.u;
}
__device__ __forceinline__ u64 pack_fi(float a, int b) {
    union { struct { float f; int i; } s; u64 u; } x; x.s.f = a; x.s.i = b; return x.u;
}
__device__ __forceinline__ float lo_f(u64 v) { union { u64 u; float f[2]; } x; x.u = v; return x.f[0]; }
__device__ __forceinline__ float hi_f(u64 v) { union { u64 u; float f[2]; } x; x.u = v; return x.f[1]; }
__device__ __forceinline__ int   hi_i(u64 v) { union { u64 u; int i[2]; } x; x.u = v; return x.i[1]; }

// Fence-free grid barrier: sc1 data is already at MALL when __syncthreads
// drains vmcnt, so arrival is one relaxed agent fetch_add; exit is a relaxed
// poll. Bounded spin: fails loud, never hangs.
__device__ __forceinline__ void grid_bar(int* bar, int target) {
    __syncthreads();
    if (threadIdx.x == 0) {
        __builtin_amdgcn_s_waitcnt(0);
        __hip_atomic_fetch_add(bar, 1, __ATOMIC_RELAXED, __HIP_MEMORY_SCOPE_AGENT);
        long guard = 0;
        while (__hip_atomic_load(bar, __ATOMIC_RELAXED, __HIP_MEMORY_SCOPE_AGENT) < target) {
            __builtin_amdgcn_s_sleep(2);
            if (++guard > (1L << 26)) break;
        }
    }
    __syncthreads();
}

__global__ __launch_bounds__(NTHR) void k_fused(const float* __restrict__ det,
                                                float* __restrict__ out,
                                                int* counters,
                                                u64* pA, u64* pB, u64* pS, u32* pC,
                                                float* surv) {
    __shared__ float lds[ROWS_PB * ROW];   // 46240 B, reused across phases
    __shared__ int nkeep, base;
    const int tid  = threadIdx.x;
    const int bid  = blockIdx.x;
    const int gidx = bid * NTHR + tid;
    int* bar = counters + CTR_BAR;

    // ---------------- Phase B: filter + argmax + bin (batch 0) ----------------
    {
        const int row0 = bid * ROWS_PB;
        int nrows = N_BOX - row0;
        if (nrows > ROWS_PB) nrows = ROWS_PB;
        if (nrows > 0) {
            const int nflt = nrows * ROW;
            const float* src = det + (size_t)row0 * ROW;  // 46240*bid bytes: 16B aligned
            const int n4 = nflt >> 2;
            float4* l4 = (float4*)lds;
            const float4* s4 = (const float4*)src;
            #pragma unroll 4
            for (int j = tid; j < n4; j += NTHR) l4[j] = s4[j];
            for (int j = (n4 << 2) + tid; j < nflt; j += NTHR) lds[j] = src[j];
            __syncthreads();
            if (tid < nrows) {
                const float* p = lds + tid * ROW;
                float obj = p[4];
                if (obj >= CONF_T) {
                    float cx = p[0], cy = p[1], w = p[2], h = p[3];
                    float hw = w / 2.0f, hh = h / 2.0f;
                    // first-argmax over 80 classes (strict > keeps first = jnp.argmax)
                    float best = p[5]; int bcls = 0;
                    for (int c = 1; c < N_CLS; ++c) {
                        float v = p[5 + c];
                        if (v > best) { best = v; bcls = c; }
                    }
                    int pos = atomicAdd(&counters[bcls * CTR_STRIDE], 1);  // own cacheline
                    if (pos < KMAX) {
                        int o = bcls * KMAX + pos;
                        AT_ST64(&pA[o], pack_ff(cx - hw, cy - hh));
                        AT_ST64(&pB[o], pack_ff(cx + hw, cy + hh));
                        AT_ST64(&pS[o], pack_fi(obj * best, row0 + tid));
                        AT_ST32(&pC[o], __float_as_uint(best));
                    }
                }
            }
        }
    }
    grid_bar(bar, NBLK);

    // ---------------- Phase C: per-class NMS (block == class) ----------------
    {
        // carve NMS arrays out of the staging LDS (9.25 KB < 46 KB)
        float* rsc   = lds;                        // [KMAX]
        int*   ridx  = (int*)(lds + KMAX);         // [KMAX]
        float* sx1   = lds + 2 * KMAX;
        float* sy1   = lds + 3 * KMAX;
        float* sx2   = lds + 4 * KMAX;
        float* sy2   = lds + 5 * KMAX;
        float* scf   = lds + 6 * KMAX;
        float* keepc = lds + 7 * KMAX;
        unsigned char* alive = (unsigned char*)(lds + 8 * KMAX);

        const int c = bid;
        if (tid == 0) nkeep = 0;
        int k = AT_LD32((u32*)&counters[c * CTR_STRIDE]);
        if (k > KMAX) k = KMAX;

        for (int i = tid; i < k; i += NTHR) {
            u64 si = AT_LD64(&pS[c * KMAX + i]);
            rsc[i] = lo_f(si); ridx[i] = hi_i(si);
        }
        __syncthreads();

        // rank = #{j : score[j] > score[i] or (==, idx[j] < idx[i])} -> stable desc
        for (int i = tid; i < k; i += NTHR) {
            float s = rsc[i]; int id = ridx[i]; int r = 0;
            for (int j = 0; j < k; ++j) {
                float sj = rsc[j];
                r += (sj > s) || (sj == s && ridx[j] < id);
            }
            int o = c * KMAX + i;
            u64 a = AT_LD64(&pA[o]);
            u64 b = AT_LD64(&pB[o]);
            sx1[r] = lo_f(a); sy1[r] = hi_f(a);
            sx2[r] = lo_f(b); sy2[r] = hi_f(b);
            scf[r] = __uint_as_float(AT_LD32(&pC[o]));
            alive[r] = 1;
        }
        __syncthreads();

        // greedy NMS with the reference's exact IoU arithmetic
        for (int i = 0; i < k; ++i) {
            bool a = (alive[i] != 0);
            __syncthreads();          // all read alive[i] before thread0 clears it
            if (a) {
                if (tid == 0) { keepc[nkeep++] = scf[i]; alive[i] = 0; }
                float px1 = sx1[i], py1 = sy1[i], px2 = sx2[i], py2 = sy2[i];
                float a1 = ((px2 - px1) + 1.0f) * ((py2 - py1) + 1.0f);
                for (int j = i + 1 + tid; j < k; j += NTHR) {
                    if (!alive[j]) continue;
                    float ix1 = fmaxf(px1, sx1[j]);
                    float iy1 = fmaxf(py1, sy1[j]);
                    float ix2 = fminf(px2, sx2[j]);
                    float iy2 = fminf(py2, sy2[j]);
                    float iw = fmaxf((ix2 - ix1) + 1.0f, 0.0f);
                    float ih = fmaxf((iy2 - iy1) + 1.0f, 0.0f);
                    float inter = iw * ih;
                    float a2 = ((sx2[j] - sx1[j]) + 1.0f) * ((sy2[j] - sy1[j]) + 1.0f);
                    float den = ((a1 + a2) - inter) + 1e-16f;
                    if (inter / den > NMS_T) alive[j] = 0;
                }
            }
            __syncthreads();          // suppression visible before next iteration
        }

        if (tid == 0) base = atomicAdd(&counters[CTR_SURV], nkeep);
        __syncthreads();
        int nb = nkeep, b = base;
        for (int i = tid; i < nb; i += NTHR) {
            int o = b + i;
            if (o < SURV_N) AT_STF(&surv[o], keepc[i]);
        }
    }
    grid_bar(bar, 2 * NBLK);

    // ---------------- Phase D: rank-scatter + tail fill ----------------
    // Ranks (ties broken by surv index) form a permutation of 0..m-1, so the
    // scatter covers out[0..m-1] exactly once; fill out[m..OUT_N-1] with NEG.
    {
        int m = AT_LD32((u32*)&counters[CTR_SURV]); if (m > SURV_N) m = SURV_N;
        float* slds = lds;                         // reuse staging LDS (16 KB max)
        for (int i = tid; i < m; i += NTHR) slds[i] = AT_LDF(&surv[i]);
        __syncthreads();

        const int lane = tid & 63;
        const int wid  = gidx >> 6;                      // 0..319
        for (int g = wid; g < m; g += NBLK * (NTHR / 64)) {
            const float v = slds[g];
            int cnt = 0;
            for (int j = lane; j < m; j += 64) {
                float sj = slds[j];
                cnt += (sj > v) || (sj == v && j < g);
            }
            #pragma unroll
            for (int off = 32; off > 0; off >>= 1) cnt += __shfl_down(cnt, off, 64);
            if (lane == 0 && cnt < OUT_N) out[cnt] = v;
        }
        for (int i = m + gidx; i < OUT_N; i += NBLK * NTHR) out[i] = NEGV;
    }
}

extern "C" void kernel_launch(void* const* d_in, const int* in_sizes, int n_in,
                              void* d_out, int out_size, void* d_ws, size_t ws_size,
                              hipStream_t stream) {
    const float* det = (const float*)d_in[0];
    float* out = (float*)d_out;

    const size_t NB = (size_t)N_CLS * KMAX;     // 20480 entries
    char* p = (char*)d_ws;
    int*   counters = (int*)p;  p += 16384;     // 82 spread counters (128B each)
    u64*   pA   = (u64*)p;      p += NB * 8;    // (x1,y1)
    u64*   pB   = (u64*)p;      p += NB * 8;    // (x2,y2)
    u64*   pS   = (u64*)p;      p += NB * 8;    // (score, idx)
    u32*   pC   = (u32*)p;      p += NB * 4;    // conf
    float* surv = (float*)p;                    // SURV_N floats

    hipMemsetAsync(d_ws, 0, CTR_BYTES, stream);   // counters + barrier, every call
    hipLaunchKernelGGL(k_fused, dim3(NBLK), dim3(NTHR), 0, stream,
                       det, out, counters, pA, pB, pS, pC, surv);
}

// Round 11
// 45.477 us; speedup vs baseline: 1.0638x; 1.0603x over previous
//
#include <hip/hip_runtime.h>

// Match XLA's elementwise f32 exactly: no FMA contraction on the decision path.
#pragma clang fp contract(off)

#define N_BOX   10647
#define N_CLS   80
#define ROW     85
#define CONF_T  0.8f
#define NMS_T   0.4f
#define NEGV    -1000000000.0f
#define KMAX    256       // max boxes per class (expected ~27)
#define OUT_N   3000
#define SURV_N  4096      // survivors cap (expected ~2000)
#define ROWS_PB 56        // rows per block in k_stage; 56*85*4 = 19040 B LDS
#define NBLK_B  ((N_BOX + ROWS_PB - 1) / ROWS_PB)   // 191 blocks
#define CTR_STRIDE 32     // one counter per 128B cacheline
#define CTR_SURV (80 * CTR_STRIDE)
#define CTR_BYTES (82 * 128)

typedef unsigned long long u64;
typedef unsigned int u32;

__device__ __forceinline__ u64 pack_ff(float a, float b) {
    union { float f[2]; u64 u; } x; x.f[0] = a; x.f[1] = b; return x.u;
}
__device__ __forceinline__ u64 pack_fi(float a, int b) {
    union { struct { float f; int i; } s; u64 u; } x; x.s.f = a; x.s.i = b; return x.u;
}
__device__ __forceinline__ float lo_f(u64 v) { union { u64 u; float f[2]; } x; x.u = v; return x.f[0]; }
__device__ __forceinline__ float hi_f(u64 v) { union { u64 u; float f[2]; } x; x.u = v; return x.f[1]; }
__device__ __forceinline__ int   hi_i(u64 v) { union { u64 u; int i[2]; } x; x.u = v; return x.i[1]; }

// ---------- Kernel 1: stage + filter + argmax + bin, and NEG-prefill out ----------
__global__ __launch_bounds__(256) void k_stage(const float* __restrict__ det,
                                               float* __restrict__ out,
                                               int* __restrict__ counters,
                                               u64* __restrict__ pA,
                                               u64* __restrict__ pB,
                                               u64* __restrict__ pS,
                                               u32* __restrict__ pC) {
    __shared__ float lds[ROWS_PB * ROW];   // 19040 B
    const int tid  = threadIdx.x;
    const int bid  = blockIdx.x;
    const int gidx = bid * 256 + tid;

    // NEG-prefill output (covers [0, OUT_N); k_rank later overwrites [0, m))
    if (gidx < OUT_N) out[gidx] = NEGV;

    const int row0 = bid * ROWS_PB;
    int nrows = N_BOX - row0; if (nrows > ROWS_PB) nrows = ROWS_PB;
    if (nrows <= 0) return;

    const int nflt = nrows * ROW;
    const float* src = det + (size_t)row0 * ROW;   // 19040*bid bytes: 16B aligned
    const int n4 = nflt >> 2;
    float4* l4 = (float4*)lds;
    const float4* s4 = (const float4*)src;
    for (int j = tid; j < n4; j += 256) l4[j] = s4[j];
    for (int j = (n4 << 2) + tid; j < nflt; j += 256) lds[j] = src[j];
    __syncthreads();

    if (tid < nrows) {
        const float* p = lds + tid * ROW;
        float obj = p[4];
        if (obj >= CONF_T) {
            float cx = p[0], cy = p[1], w = p[2], h = p[3];
            float hw = w / 2.0f, hh = h / 2.0f;
            // first-argmax over 80 classes (strict > keeps first = jnp.argmax)
            float best = p[5]; int bcls = 0;
            for (int c = 1; c < N_CLS; ++c) {
                float v = p[5 + c];
                if (v > best) { best = v; bcls = c; }
            }
            int pos = atomicAdd(&counters[bcls * CTR_STRIDE], 1);
            if (pos < KMAX) {
                int o = bcls * KMAX + pos;
                pA[o] = pack_ff(cx - hw, cy - hh);
                pB[o] = pack_ff(cx + hw, cy + hh);
                pS[o] = pack_fi(obj * best, row0 + tid);
                pC[o] = __float_as_uint(best);
            }
        }
    }
}

// ---------- Kernel 2: per-class NMS (block == class) ----------
__global__ __launch_bounds__(256) void k_nms(const u64* __restrict__ pA,
                                             const u64* __restrict__ pB,
                                             const u64* __restrict__ pS,
                                             const u32* __restrict__ pC,
                                             int* __restrict__ counters,
                                             float* __restrict__ surv) {
    __shared__ float rsc[KMAX]; __shared__ int ridx[KMAX];
    __shared__ float sx1[KMAX], sy1[KMAX], sx2[KMAX], sy2[KMAX], scf[KMAX];
    __shared__ unsigned char alive[KMAX];
    __shared__ float keepc[KMAX];
    __shared__ int nkeep, base;

    const int c = blockIdx.x;
    const int tid = threadIdx.x;
    if (tid == 0) nkeep = 0;

    int k = counters[c * CTR_STRIDE]; if (k > KMAX) k = KMAX;

    for (int i = tid; i < k; i += 256) {
        u64 si = pS[c * KMAX + i];
        rsc[i] = lo_f(si); ridx[i] = hi_i(si);
    }
    __syncthreads();

    // rank = #{j : score[j] > score[i] or (==, idx[j] < idx[i])} -> stable desc
    for (int i = tid; i < k; i += 256) {
        float s = rsc[i]; int id = ridx[i]; int r = 0;
        for (int j = 0; j < k; ++j) {
            float sj = rsc[j];
            r += (sj > s) || (sj == s && ridx[j] < id);
        }
        int o = c * KMAX + i;
        u64 a = pA[o], b = pB[o];
        sx1[r] = lo_f(a); sy1[r] = hi_f(a);
        sx2[r] = lo_f(b); sy2[r] = hi_f(b);
        scf[r] = __uint_as_float(pC[o]);
        alive[r] = 1;
    }
    __syncthreads();

    // greedy NMS with the reference's exact IoU arithmetic
    for (int i = 0; i < k; ++i) {
        bool a = (alive[i] != 0);
        __syncthreads();              // all read alive[i] before thread0 clears it
        if (a) {
            if (tid == 0) { keepc[nkeep++] = scf[i]; alive[i] = 0; }
            float px1 = sx1[i], py1 = sy1[i], px2 = sx2[i], py2 = sy2[i];
            float a1 = ((px2 - px1) + 1.0f) * ((py2 - py1) + 1.0f);
            for (int j = i + 1 + tid; j < k; j += 256) {
                if (!alive[j]) continue;
                float ix1 = fmaxf(px1, sx1[j]);
                float iy1 = fmaxf(py1, sy1[j]);
                float ix2 = fminf(px2, sx2[j]);
                float iy2 = fminf(py2, sy2[j]);
                float iw = fmaxf((ix2 - ix1) + 1.0f, 0.0f);
                float ih = fmaxf((iy2 - iy1) + 1.0f, 0.0f);
                float inter = iw * ih;
                float a2 = ((sx2[j] - sx1[j]) + 1.0f) * ((sy2[j] - sy1[j]) + 1.0f);
                float den = ((a1 + a2) - inter) + 1e-16f;
                if (inter / den > NMS_T) alive[j] = 0;
            }
        }
        __syncthreads();              // suppression visible before next iteration
    }

    if (tid == 0) base = atomicAdd(&counters[CTR_SURV], nkeep);
    __syncthreads();
    int nb = nkeep, b = base;
    for (int i = tid; i < nb; i += 256) {
        int o = b + i;
        if (o < SURV_N) surv[o] = keepc[i];
    }
}

// ---------- Kernel 3: rank-scatter (wave per element, 320 waves) ----------
// Ranks (ties broken by surv index) form a permutation of 0..m-1; out tail
// already NEG from k_stage's prefill.
__global__ __launch_bounds__(256) void k_rank(const float* __restrict__ surv,
                                              const int* __restrict__ counters,
                                              float* __restrict__ out) {
    __shared__ float slds[SURV_N];     // 16 KB
    const int tid = threadIdx.x;
    int m = counters[CTR_SURV]; if (m > SURV_N) m = SURV_N;

    for (int i = tid; i < m; i += 256) slds[i] = surv[i];
    __syncthreads();

    const int lane = tid & 63;
    const int wid  = (blockIdx.x * 256 + tid) >> 6;      // 0..319
    for (int g = wid; g < m; g += N_CLS * 4) {
        const float v = slds[g];
        int cnt = 0;
        for (int j = lane; j < m; j += 64) {
            float sj = slds[j];
            cnt += (sj > v) || (sj == v && j < g);
        }
        #pragma unroll
        for (int off = 32; off > 0; off >>= 1) cnt += __shfl_down(cnt, off, 64);
        if (lane == 0 && cnt < OUT_N) out[cnt] = v;
    }
}

extern "C" void kernel_launch(void* const* d_in, const int* in_sizes, int n_in,
                              void* d_out, int out_size, void* d_ws, size_t ws_size,
                              hipStream_t stream) {
    const float* det = (const float*)d_in[0];
    float* out = (float*)d_out;

    const size_t NB = (size_t)N_CLS * KMAX;     // 20480 entries
    char* p = (char*)d_ws;
    int*   counters = (int*)p;  p += 16384;     // spread counters (128B each)
    u64*   pA   = (u64*)p;      p += NB * 8;    // (x1,y1)
    u64*   pB   = (u64*)p;      p += NB * 8;    // (x2,y2)
    u64*   pS   = (u64*)p;      p += NB * 8;    // (score, idx)
    u32*   pC   = (u32*)p;      p += NB * 4;    // conf
    float* surv = (float*)p;                    // SURV_N floats

    hipMemsetAsync(counters, 0, CTR_BYTES, stream);
    hipLaunchKernelGGL(k_stage, dim3(NBLK_B), dim3(256), 0, stream,
                       det, out, counters, pA, pB, pS, pC);
    hipLaunchKernelGGL(k_nms,   dim3(N_CLS), dim3(256), 0, stream,
                       pA, pB, pS, pC, counters, surv);
    hipLaunchKernelGGL(k_rank,  dim3(N_CLS), dim3(256), 0, stream,
                       surv, counters, out);
}